// Round 2
// baseline (216.527 us; speedup 1.0000x reference)
//
#include <hip/hip_runtime.h>
#include <hip/hip_bf16.h>

// Problem constants (fixed by reference): B=8, T=2048, C=1024, D=64
#define TB 8
#define TT 2048
#define TC 1024
#define TD 64
#define SP 72   // LDS row stride in bf16 elems (for P round-trip buffer)

typedef __attribute__((ext_vector_type(8))) short bf16x8;
typedef __attribute__((ext_vector_type(4))) float f32x4;

__device__ __forceinline__ short f2bf(float f) {
    union { float f; unsigned u; } v; v.f = f;
    unsigned r = v.u + 0x7fffu + ((v.u >> 16) & 1u);   // RNE
    return (short)(r >> 16);
}

__device__ __forceinline__ bf16x8 cvt8(float4 a, float4 b) {
    bf16x8 r;
    r[0] = f2bf(a.x); r[1] = f2bf(a.y); r[2] = f2bf(a.z); r[3] = f2bf(a.w);
    r[4] = f2bf(b.x); r[5] = f2bf(b.y); r[6] = f2bf(b.z); r[7] = f2bf(b.w);
    return r;
}

// ---------------------------------------------------------------------------
// Kernel 1: fuse + transpose weights to bf16. Wt[n][k], n: 0..63=Wk, 64..127=Wq
// (pre-scaled by 0.125 = d^-0.5, exact), 128..191=Wv.  W* are [1024][64] fp32.
// ---------------------------------------------------------------------------
__global__ __launch_bounds__(256) void convert_w(const float* __restrict__ Wk,
                                                 const float* __restrict__ Wq,
                                                 const float* __restrict__ Wv,
                                                 short* __restrict__ Wt) {
    int n = blockIdx.x;                 // 0..191
    const float* src; float scale = 1.0f;
    int c = n & 63;
    if (n < 64)       { src = Wk; }
    else if (n < 128) { src = Wq; scale = 0.125f; }
    else              { src = Wv; }
    for (int kk = threadIdx.x; kk < TC; kk += 256)
        Wt[n * TC + kk] = f2bf(src[kk * TD + c] * scale);
}

// ---------------------------------------------------------------------------
// Kernel 2: QKV projection, LDS-free / barrier-free.
// Grid: 768 blocks = 256 m-groups (64 rows) x 3 outputs. Block = 4 waves; wave
// w computes rows [mg*64+16w, +16) x 64 cols of output oid (0=k,1=q,2=v).
// A-fragments read directly from fp32 x (convert in-reg), B from bf16 Wt
// (all 4 waves read the same 128KB Wt slice -> L1 hits).
// 3072 waves total = 12 waves/CU.
// ---------------------------------------------------------------------------
__global__ __launch_bounds__(256) void qkv_proj(const float* __restrict__ x,
                                                const short* __restrict__ Wt,
                                                short* __restrict__ qb,
                                                short* __restrict__ kb,
                                                short* __restrict__ vb) {
    const int tid  = threadIdx.x;
    const int bid  = blockIdx.x;        // 0..767
    const int mg   = bid / 3;           // 0..255
    const int oid  = bid % 3;           // 0=k,1=q,2=v  (matches Wt row blocks)
    const int wv   = tid >> 6, lane = tid & 63;
    const int l15  = lane & 15, quad = lane >> 4;
    const int row0 = mg * 64 + wv * 16;

    f32x4 acc[4];
#pragma unroll
    for (int i = 0; i < 4; ++i) acc[i] = (f32x4){0.f, 0.f, 0.f, 0.f};

    const float* xp = x  + (size_t)(row0 + l15) * TC + quad * 8;
    const short* wp = Wt + (size_t)(oid * 64 + l15) * TC + quad * 8;

#pragma unroll 2
    for (int k0 = 0; k0 < TC; k0 += 64) {
        float4 f0 = *(const float4*)(xp + k0);
        float4 f1 = *(const float4*)(xp + k0 + 4);
        float4 f2 = *(const float4*)(xp + k0 + 32);
        float4 f3 = *(const float4*)(xp + k0 + 36);
        bf16x8 a0 = cvt8(f0, f1);
        bf16x8 a1 = cvt8(f2, f3);
#pragma unroll
        for (int nt = 0; nt < 4; ++nt) {
            bf16x8 b0 = *(const bf16x8*)(wp + (size_t)nt * 16 * TC + k0);
            bf16x8 b1 = *(const bf16x8*)(wp + (size_t)nt * 16 * TC + k0 + 32);
            acc[nt] = __builtin_amdgcn_mfma_f32_16x16x32_bf16(a0, b0, acc[nt], 0, 0, 0);
            acc[nt] = __builtin_amdgcn_mfma_f32_16x16x32_bf16(a1, b1, acc[nt], 0, 0, 0);
        }
    }
    short* dst = (oid == 0) ? kb : (oid == 1) ? qb : vb;
#pragma unroll
    for (int nt = 0; nt < 4; ++nt)
#pragma unroll
        for (int r = 0; r < 4; ++r)
            dst[(size_t)(row0 + quad * 4 + r) * TD + nt * 16 + l15] = f2bf(acc[nt][r]);
}

// ---------------------------------------------------------------------------
// Kernel 3: v[b][t][d] -> vt[b][d][t]  (so PV B-operand reads are contiguous)
// ---------------------------------------------------------------------------
__global__ __launch_bounds__(256) void transpose_v(const short* __restrict__ vb,
                                                   short* __restrict__ vt) {
    __shared__ short Tl[64 * SP];
    const int tid = threadIdx.x;
    const int tc  = blockIdx.x;   // 0..31 (t-chunk)
    const int b   = blockIdx.y;
    const int rr  = tid >> 2;     // 0..63
    const int c0  = (tid & 3) << 4;
    {
        const uint4* s = (const uint4*)(vb + (size_t)(b * TT + tc * 64 + rr) * TD + c0);
        uint4 u0 = s[0], u1 = s[1];
        *(uint4*)&Tl[rr * SP + c0]     = u0;
        *(uint4*)&Tl[rr * SP + c0 + 8] = u1;
    }
    __syncthreads();
    alignas(16) short t16[16];
#pragma unroll
    for (int j = 0; j < 16; ++j) t16[j] = Tl[(c0 + j) * SP + rr];
    uint4* d = (uint4*)(vt + (size_t)(b * TD + rr) * TT + tc * 64 + c0);
    d[0] = *(uint4*)&t16[0];
    d[1] = *(uint4*)&t16[8];
}

// ---------------------------------------------------------------------------
// Kernel 4: flash attention, per-wave K-split.
// Grid: (128, 8) blocks; block = 4 waves; all waves share a 16-row Q-tile.
// Wave w handles K-tiles kt = w, w+4, ... (64-wide), reading K/V fragments
// directly from global (L2-resident). No __syncthreads in the main loop.
// End: merge the 4 waves' online-softmax states through LDS.
// it reversed so the longest blocks launch first (balance heuristic).
// ---------------------------------------------------------------------------
__global__ __launch_bounds__(256) void attn(const short* __restrict__ qb,
                                            const short* __restrict__ kb,
                                            const short* __restrict__ vt,
                                            float* __restrict__ out) {
    __shared__ short Ps[4][16 * SP];
    __shared__ float Ow[4][16][64];
    __shared__ float Mw[4][16];
    __shared__ float Lw[4][16];
    const int tid  = threadIdx.x;
    const int it   = (int)gridDim.x - 1 - (int)blockIdx.x;   // 0..127
    const int b    = blockIdx.y;
    const int wv   = tid >> 6, lane = tid & 63;
    const int l15  = lane & 15, quad = lane >> 4;
    const int q0   = it * 16;
    const int KT   = (it >> 2) + 1;     // # of 64-wide K tiles needed
    const float L2E = 1.4426950408889634f;

    const size_t qoff = (size_t)(b * TT + q0 + l15) * TD + quad * 8;
    bf16x8 aq0 = *(const bf16x8*)(qb + qoff);
    bf16x8 aq1 = *(const bf16x8*)(qb + qoff + 32);

    f32x4 O[4];
#pragma unroll
    for (int i = 0; i < 4; ++i) O[i] = (f32x4){0.f, 0.f, 0.f, 0.f};
    float mrun[4], lrun[4];
#pragma unroll
    for (int r = 0; r < 4; ++r) { mrun[r] = -INFINITY; lrun[r] = 0.f; }

    for (int kt = wv; kt < KT; kt += 4) {
        const short* kp = kb + (size_t)(b * TT + kt * 64 + l15) * TD + quad * 8;
        f32x4 S[4];
#pragma unroll
        for (int nt = 0; nt < 4; ++nt) {
            bf16x8 b0 = *(const bf16x8*)(kp + (size_t)nt * 16 * TD);
            bf16x8 b1 = *(const bf16x8*)(kp + (size_t)nt * 16 * TD + 32);
            S[nt] = (f32x4){0.f, 0.f, 0.f, 0.f};
            S[nt] = __builtin_amdgcn_mfma_f32_16x16x32_bf16(aq0, b0, S[nt], 0, 0, 0);
            S[nt] = __builtin_amdgcn_mfma_f32_16x16x32_bf16(aq1, b1, S[nt], 0, 0, 0);
        }
        if (kt == KT - 1) {           // diagonal tile: causal mask
#pragma unroll
            for (int nt = 0; nt < 4; ++nt) {
                int scol = kt * 64 + nt * 16 + l15;
#pragma unroll
                for (int r = 0; r < 4; ++r)
                    if (scol > q0 + quad * 4 + r) S[nt][r] = -INFINITY;
            }
        }
        float alpha[4];
#pragma unroll
        for (int r = 0; r < 4; ++r) {
            float v = fmaxf(fmaxf(S[0][r], S[1][r]), fmaxf(S[2][r], S[3][r]));
            v = fmaxf(v, __shfl_xor(v, 1));
            v = fmaxf(v, __shfl_xor(v, 2));
            v = fmaxf(v, __shfl_xor(v, 4));
            v = fmaxf(v, __shfl_xor(v, 8));
            float mnew = fmaxf(mrun[r], v);
            alpha[r] = exp2f((mrun[r] - mnew) * L2E);
            mrun[r] = mnew;
        }
        float ps[4] = {0.f, 0.f, 0.f, 0.f};
#pragma unroll
        for (int nt = 0; nt < 4; ++nt) {
#pragma unroll
            for (int r = 0; r < 4; ++r) {
                float p = exp2f((S[nt][r] - mrun[r]) * L2E);
                ps[r] += p;
                Ps[wv][(quad * 4 + r) * SP + nt * 16 + l15] = f2bf(p);
            }
        }
#pragma unroll
        for (int r = 0; r < 4; ++r) {
            float v = ps[r];
            v += __shfl_xor(v, 1);
            v += __shfl_xor(v, 2);
            v += __shfl_xor(v, 4);
            v += __shfl_xor(v, 8);
            lrun[r] = alpha[r] * lrun[r] + v;
        }
#pragma unroll
        for (int i = 0; i < 4; ++i)
#pragma unroll
            for (int r = 0; r < 4; ++r) O[i][r] *= alpha[r];

        bf16x8 p0 = *(bf16x8*)&Ps[wv][l15 * SP + quad * 8];
        bf16x8 p1 = *(bf16x8*)&Ps[wv][l15 * SP + quad * 8 + 32];
        const short* vp = vt + (size_t)(b * TD + l15) * TT + kt * 64 + quad * 8;
#pragma unroll
        for (int dt = 0; dt < 4; ++dt) {
            bf16x8 b0 = *(const bf16x8*)(vp + (size_t)dt * 16 * TT);
            bf16x8 b1 = *(const bf16x8*)(vp + (size_t)dt * 16 * TT + 32);
            O[dt] = __builtin_amdgcn_mfma_f32_16x16x32_bf16(p0, b0, O[dt], 0, 0, 0);
            O[dt] = __builtin_amdgcn_mfma_f32_16x16x32_bf16(p1, b1, O[dt], 0, 0, 0);
        }
    }

    // spill per-wave state
    if (l15 == 0) {
#pragma unroll
        for (int r = 0; r < 4; ++r) {
            Mw[wv][quad * 4 + r] = mrun[r];
            Lw[wv][quad * 4 + r] = lrun[r];
        }
    }
#pragma unroll
    for (int dt = 0; dt < 4; ++dt)
#pragma unroll
        for (int r = 0; r < 4; ++r)
            Ow[wv][quad * 4 + r][dt * 16 + l15] = O[dt][r];
    __syncthreads();

    // merge: thread handles col = tid&63, rows tid>>6 + {0,4,8,12}
    const int col = tid & 63;
    const int rb  = tid >> 6;
    for (int rr = rb; rr < 16; rr += 4) {
        float m0 = Mw[0][rr], m1 = Mw[1][rr], m2 = Mw[2][rr], m3 = Mw[3][rr];
        float M = fmaxf(fmaxf(m0, m1), fmaxf(m2, m3));
        float s0 = exp2f((m0 - M) * L2E);
        float s1 = exp2f((m1 - M) * L2E);
        float s2 = exp2f((m2 - M) * L2E);
        float s3 = exp2f((m3 - M) * L2E);
        float L = s0 * Lw[0][rr] + s1 * Lw[1][rr] + s2 * Lw[2][rr] + s3 * Lw[3][rr];
        float o = s0 * Ow[0][rr][col] + s1 * Ow[1][rr][col]
                + s2 * Ow[2][rr][col] + s3 * Ow[3][rr][col];
        out[(size_t)(b * TT + q0 + rr) * TD + col] = o / L;
    }
}

// ---------------------------------------------------------------------------
extern "C" void kernel_launch(void* const* d_in, const int* in_sizes, int n_in,
                              void* d_out, int out_size, void* d_ws, size_t ws_size,
                              hipStream_t stream) {
    const float* x  = (const float*)d_in[0];
    const float* Wk = (const float*)d_in[1];
    const float* Wq = (const float*)d_in[2];
    const float* Wv = (const float*)d_in[3];
    float* out = (float*)d_out;

    char* ws = (char*)d_ws;
    // layout: Wt bf16 [192][1024] | qb | kb | vb | vt  (each 16384*64 bf16 = 2MB)
    short* Wt = (short*)(ws);
    short* qb = (short*)(ws + 524288);
    short* kb = (short*)(ws + 2621440);
    short* vb = (short*)(ws + 4718592);
    short* vt = (short*)(ws + 6815744);

    convert_w<<<dim3(192), dim3(256), 0, stream>>>(Wk, Wq, Wv, Wt);
    qkv_proj<<<dim3(768), dim3(256), 0, stream>>>(x, Wt, qb, kb, vb);
    transpose_v<<<dim3(32, 8), dim3(256), 0, stream>>>(vb, vt);
    attn<<<dim3(128, 8), dim3(256), 0, stream>>>(qb, kb, vt, out);
}